// Round 16
// baseline (194.577 us; speedup 1.0000x reference)
//
#include <hip/hip_runtime.h>

// Trilinear feature-grid interpolation, v11b: wave-autonomous gather.
// grid layout: [R][R][R][3] = [z][y][x][c], R=256, fp32 (192 MB).
//
// v11 failed correctness: epilogue guard staged layers only up to z0+15
// (`zc < 14`), so step zc=15 read a stale upper layer. Fix: `zc < 15`
// stages z0+16 at zc=14. No other changes vs v11 — this cleanly measures
// the wave-autonomy hypothesis:
// each WAVE owns a (16z x 8y x 64x) column with a private 2-layer LDS
// window (7KB/layer); per z-step: wave-level s_waitcnt vmcnt(0) -> compute
// ~64 pts (1/lane) -> issue next layer's 7 DMAs. NO __syncthreads.
// 8 independent wave-streams/CU.

#define NB      32768
#define CAP     128u
#define SBLK    1024
#define GBLK    256               // 4 waves per gather block
#define LAYF4   441               // 9 rows x 49 float4 per layer
#define LAYF    1764              // floats per layer (7056 B)
#define GRIDF4  12582912

// ws layout: binned[32768*128] float4 = 64MB, then cur[32768]
#define CUR_OFF   67108864u
#define NEEDED    (67108864u + 131072u)

typedef float f4v __attribute__((ext_vector_type(4)));
typedef float f2v __attribute__((ext_vector_type(2)));
typedef f4v f4u __attribute__((aligned(8)));
typedef f2v f2u __attribute__((aligned(8)));

__device__ __forceinline__ void cell_of(float p, int& l, float& t) {
    float s = p * 255.0f;
    int v = (int)floorf(s);
    v = v < 0 ? 0 : (v > 254 ? 254 : v);
    l = v;
    t = s - (float)v;
}

// bin: [zl:8][yb:5][xq:2]
__device__ __forceinline__ int fine_bin3(float px, float py, float pz) {
    int xl, yl, zl; float tx, ty, tz;
    cell_of(px, xl, tx);
    cell_of(py, yl, ty);
    cell_of(pz, zl, tz);
    return (zl << 7) | ((yl >> 3) << 2) | (xl >> 6);
}

__device__ __forceinline__ void direct_lerp(const float* __restrict__ grid,
                                            float* __restrict__ out, int i,
                                            int xl, int yl, int zl,
                                            float tx, float ty, float tz) {
    int b00 = (zl * 65536 + yl * 256 + xl) * 3;
    int b01 = b00 + 768, b10 = b00 + 196608, b11 = b10 + 768;
    float s00[6], s01[6], s10[6], s11[6];
#pragma unroll
    for (int k = 0; k < 6; ++k) s00[k] = grid[b00 + k];
#pragma unroll
    for (int k = 0; k < 6; ++k) s01[k] = grid[b01 + k];
#pragma unroll
    for (int k = 0; k < 6; ++k) s10[k] = grid[b10 + k];
#pragma unroll
    for (int k = 0; k < 6; ++k) s11[k] = grid[b11 + k];
#pragma unroll
    for (int c = 0; c < 3; ++c) {
        float c00 = s00[c] * (1.0f - tx) + s00[c + 3] * tx;
        float c01 = s01[c] * (1.0f - tx) + s01[c + 3] * tx;
        float c10 = s10[c] * (1.0f - tx) + s10[c + 3] * tx;
        float c11 = s11[c] * (1.0f - tx) + s11[c + 3] * tx;
        float c0 = c00 * (1.0f - ty) + c01 * ty;
        float c1 = c10 * (1.0f - ty) + c11 * ty;
        out[3 * i + c] = c0 * (1.0f - tz) + c1 * tz;
    }
}

// ---------------- pass 0: init cursors ----------------
__global__ __launch_bounds__(1024) void k_init(unsigned* __restrict__ cur) {
    int i = blockIdx.x * 1024 + threadIdx.x;
    if (i < NB) cur[i] = (unsigned)i * CAP;
}

// ---------------- pass 1: block-aggregated scatter (2 pts/thread) ----------------
// agg: 16384 u32 words, each two u16 bin counts (phase 1), then two u16
// within-bin base offsets (phase 2). Per-iter counts <= 2048 so no carry.
__global__ __launch_bounds__(SBLK) void k_scatter(const float* __restrict__ inp,
                                                  const float* __restrict__ grid,
                                                  float4* __restrict__ binned,
                                                  unsigned* __restrict__ cur,
                                                  float* __restrict__ out, int n) {
    __shared__ unsigned agg[NB / 2];   // 64 KB
    int t = threadIdx.x;
    int P = n >> 1;
    int stride = gridDim.x * SBLK;
    int iters = (P + stride - 1) / stride;

    if ((n & 1) && blockIdx.x == 0 && t == 0) {
        int i = n - 1;
        float px = inp[3 * i], py = inp[3 * i + 1], pz = inp[3 * i + 2];
        int b = fine_bin3(px, py, pz);
        unsigned r = atomicAdd(&cur[b], 1u);
        if (r - (unsigned)b * CAP < CAP) {
            float4 v; v.x = px; v.y = py; v.z = pz; v.w = __uint_as_float((unsigned)i);
            binned[r] = v;
        } else {
            int xl, yl, zl; float tx, ty, tz;
            cell_of(px, xl, tx); cell_of(py, yl, ty); cell_of(pz, zl, tz);
            direct_lerp(grid, out, i, xl, yl, zl, tx, ty, tz);
        }
    }

    for (int it = 0; it < iters; ++it) {
        int pr = it * stride + blockIdx.x * SBLK + t;
        for (int k = t; k < NB / 2; k += SBLK) agg[k] = 0;
        __syncthreads();
        int b0 = 0, b1 = 0; unsigned r0 = 0, r1 = 0;
        float4 p0, p1;
        bool valid = (pr < P);
        if (valid) {
            f4v a = *(const f4u*)(inp + 6 * pr);
            f2v b = *(const f2u*)(inp + 6 * pr + 4);
            p0.x = a.x; p0.y = a.y; p0.z = a.z;
            p0.w = __uint_as_float((unsigned)(2 * pr));
            p1.x = a.w; p1.y = b.x; p1.z = b.y;
            p1.w = __uint_as_float((unsigned)(2 * pr + 1));
            b0 = fine_bin3(p0.x, p0.y, p0.z);
            b1 = fine_bin3(p1.x, p1.y, p1.z);
            r0 = (atomicAdd(&agg[b0 >> 1], 1u << ((b0 & 1) << 4)) >> ((b0 & 1) << 4)) & 0xffffu;
            r1 = (atomicAdd(&agg[b1 >> 1], 1u << ((b1 & 1) << 4)) >> ((b1 & 1) << 4)) & 0xffffu;
        }
        __syncthreads();
        for (int k = t; k < NB / 2; k += SBLK) {
            unsigned w2 = agg[k];
            if (w2) {
                unsigned c0 = w2 & 0xffffu, c1 = w2 >> 16;
                unsigned o0 = 0, o1 = 0;
                if (c0) {
                    unsigned bse = atomicAdd(&cur[2 * k], c0) - (unsigned)(2 * k) * CAP;
                    o0 = bse > 0xffffu ? 0xffffu : bse;
                }
                if (c1) {
                    unsigned bse = atomicAdd(&cur[2 * k + 1], c1) - (unsigned)(2 * k + 1) * CAP;
                    o1 = bse > 0xffffu ? 0xffffu : bse;
                }
                agg[k] = o0 | (o1 << 16);
            }
        }
        __syncthreads();
        if (valid) {
            unsigned off0 = (agg[b0 >> 1] >> ((b0 & 1) << 4)) & 0xffffu;
            unsigned off1 = (agg[b1 >> 1] >> ((b1 & 1) << 4)) & 0xffffu;
            unsigned s0 = off0 + r0, s1 = off1 + r1;
            if (s0 < CAP) binned[(unsigned)b0 * CAP + s0] = p0;
            else {
                int xl, yl, zl; float tx, ty, tz;
                cell_of(p0.x, xl, tx); cell_of(p0.y, yl, ty); cell_of(p0.z, zl, tz);
                direct_lerp(grid, out, 2 * pr, xl, yl, zl, tx, ty, tz);
            }
            if (s1 < CAP) binned[(unsigned)b1 * CAP + s1] = p1;
            else {
                int xl, yl, zl; float tx, ty, tz;
                cell_of(p1.x, xl, tx); cell_of(p1.y, yl, ty); cell_of(p1.z, zl, tz);
                direct_lerp(grid, out, 2 * pr + 1, xl, yl, zl, tx, ty, tz);
            }
        }
        __syncthreads();
    }
}

// ---------------- pass 2: wave-autonomous z-walk gather ----------------
// Stage layer zg into a wave-private 7KB LDS layer: 9 y-rows x 49 float4,
// contiguous per row (784B bursts). 7 DMA instructions per wave.
#define STAGE(zg_, dstp)                                                        \
    do {                                                                        \
        int zgc = (zg_) > 255 ? 255 : (zg_);                                    \
        for (int u = lane; u < LAYF4; u += 64) {                                \
            int row = u / 49;                                                   \
            int j = u - row * 49;                                               \
            int yg = y0 + row; if (yg > 255) yg = 255;                          \
            size_t sf4 = (size_t)zgc * 49152 + (size_t)yg * 192 + (size_t)xq48 + (size_t)j; \
            if (sf4 > (size_t)(GRIDF4 - 1)) sf4 = (size_t)(GRIDF4 - 1);         \
            __builtin_amdgcn_global_load_lds(                                   \
                (const __attribute__((address_space(1))) unsigned int*)(grid + sf4 * 4), \
                (__attribute__((address_space(3))) unsigned int*)((dstp) + (size_t)u * 4), \
                16, 0, 0);                                                      \
        }                                                                       \
    } while (0)

__global__ __launch_bounds__(GBLK) void k_gather(const float4* __restrict__ binned,
                                                 const float* __restrict__ grid,
                                                 const unsigned* __restrict__ cur,
                                                 float* __restrict__ out) {
    __shared__ __align__(16) float slab[4][2][LAYF];   // 56448 B -> 2 blocks/CU
    int w    = threadIdx.x >> 6;
    int lane = threadIdx.x & 63;
    // 512 blocks x 4 waves = 2048 columns. XCD-chunked: XCD k owns cols
    // [256k, 256k+256) = 2 contiguous z-segments x all y x all x-quarters.
    int sb  = ((blockIdx.x & 7) << 6) | (blockIdx.x >> 3);   // bijective [0,512)
    int col = (sb << 2) | w;
    int zseg = col >> 7;          // 16 z-segments of 16 cells
    int yb   = (col >> 2) & 31;   // 32 y-bins of 8 cells
    int xq   = col & 3;           // 4 x-quarters of 64 cells
    int z0 = zseg << 4;
    int y0 = yb << 3;
    int x0 = xq << 6;
    int xq48 = x0 * 3 / 4;        // x offset in float4 units

    float* L0 = &slab[w][0][0];
    float* L1 = &slab[w][1][0];

    STAGE(z0, L0);
    STAGE(z0 + 1, L1);

    for (int zc = 0; zc < 16; ++zc) {
        float* A = (zc & 1) ? L1 : L0;   // layer zc   (lower)
        float* B = (zc & 1) ? L0 : L1;   // layer zc+1 (upper)

        // Wave-level drain of this wave's outstanding DMAs (no barrier).
        asm volatile("s_waitcnt vmcnt(0)" ::: "memory");
        __builtin_amdgcn_sched_barrier(0);

        int K = ((z0 + zc) << 7) | (yb << 2) | xq;
        unsigned start = (unsigned)K * CAP;
        unsigned count = cur[K] - start;
        if (count > CAP) count = CAP;

        for (unsigned p = (unsigned)lane; p < count; p += 64u) {
            float4 v = binned[start + p];
            unsigned idx = __float_as_uint(v.w);

            int xl, yl, zl; float tx, ty, tz;
            cell_of(v.x, xl, tx);
            cell_of(v.y, yl, ty);
            cell_of(v.z, zl, tz);
            int row = yl - y0;             // 0..7
            int xc  = xl - x0;             // 0..63

            int o00 = row * 196 + xc * 3;  // in layer A
            int o01 = o00 + 196;
            // same offsets in layer B for zl+1

#define SEG_READ(Lp, b, s)                                   \
            do {                                             \
                int e_ = (b) & ~1;                           \
                bool d_ = ((b) & 1) != 0;                    \
                f2v q0 = *(const f2u*)(&(Lp)[e_]);           \
                f2v q1 = *(const f2u*)(&(Lp)[e_ + 2]);       \
                f2v q2 = *(const f2u*)(&(Lp)[e_ + 4]);       \
                f2v q3 = *(const f2u*)(&(Lp)[e_ + 6]);       \
                s[0] = d_ ? q0.y : q0.x;                     \
                s[1] = d_ ? q1.x : q0.y;                     \
                s[2] = d_ ? q1.y : q1.x;                     \
                s[3] = d_ ? q2.x : q1.y;                     \
                s[4] = d_ ? q2.y : q2.x;                     \
                s[5] = d_ ? q3.x : q2.y;                     \
            } while (0)

            float s00[6], s01[6], s10[6], s11[6];
            SEG_READ(A, o00, s00);   // (zl,   yl)
            SEG_READ(A, o01, s01);   // (zl,   yl+1)
            SEG_READ(B, o00, s10);   // (zl+1, yl)
            SEG_READ(B, o01, s11);   // (zl+1, yl+1)
#undef SEG_READ

            float o[3];
#pragma unroll
            for (int c = 0; c < 3; ++c) {
                float c00 = s00[c] * (1.0f - tx) + s00[c + 3] * tx;
                float c01 = s01[c] * (1.0f - tx) + s01[c + 3] * tx;
                float c10 = s10[c] * (1.0f - tx) + s10[c + 3] * tx;
                float c11 = s11[c] * (1.0f - tx) + s11[c + 3] * tx;
                float c0 = c00 * (1.0f - ty) + c01 * ty;
                float c1 = c10 * (1.0f - ty) + c11 * ty;
                o[c] = c0 * (1.0f - tz) + c1 * tz;
            }
            float3 wv; wv.x = o[0]; wv.y = o[1]; wv.z = o[2];
            *(float3*)(out + 3 * (size_t)idx) = wv;
        }

        // Pin compute's LDS reads before reusing layer A's slot, then
        // stage layer zc+2 over it. zc<15 so layer z0+16 (upper layer of
        // step 15) IS staged at zc=14 — this was v11's bug (zc<14).
        __builtin_amdgcn_sched_barrier(0);
        if (zc < 15) STAGE(z0 + zc + 2, A);
    }
}

// ---------------- fallback: direct ----------------
__global__ __launch_bounds__(256) void k_direct(const float* __restrict__ inp,
                                                const float* __restrict__ grid,
                                                float* __restrict__ out, int n) {
    int i = blockIdx.x * blockDim.x + threadIdx.x;
    if (i >= n) return;
    int xl, yl, zl; float tx, ty, tz;
    cell_of(inp[3 * i + 0], xl, tx);
    cell_of(inp[3 * i + 1], yl, ty);
    cell_of(inp[3 * i + 2], zl, tz);
    direct_lerp(grid, out, i, xl, yl, zl, tx, ty, tz);
}

extern "C" void kernel_launch(void* const* d_in, const int* in_sizes, int n_in,
                              void* d_out, int out_size, void* d_ws, size_t ws_size,
                              hipStream_t stream) {
    const float* inp  = (const float*)d_in[0];  // [N][3]
    const float* grid = (const float*)d_in[1];  // [256][256][256][3]
    float* out = (float*)d_out;                 // [N][3]
    int n = in_sizes[0] / 3;

    if (ws_size < (size_t)NEEDED) {
        int blocks = (n + 255) / 256;
        k_direct<<<blocks, 256, 0, stream>>>(inp, grid, out, n);
        return;
    }

    char* ws = (char*)d_ws;
    float4*   binned = (float4*)ws;
    unsigned* cur    = (unsigned*)(ws + CUR_OFF);

    k_init   <<<32,  1024, 0, stream>>>(cur);
    k_scatter<<<512, SBLK, 0, stream>>>(inp, grid, binned, cur, out, n);
    k_gather <<<512, GBLK, 0, stream>>>(binned, grid, cur, out);
}

// Round 17
// 133.422 us; speedup vs baseline: 1.4584x; 1.4584x over previous
//
#include <hip/hip_runtime.h>

// Trilinear feature-grid interpolation, v12: reg-staged gather (T14).
// grid layout: [R][R][R][3] = [z][y][x][c], R=256, fp32 (192 MB).
//
// Rounds 5-16: SEVEN structurally different global_load_lds staged gathers
// all pinned at ~115us (~2.1 TB/s), while register-load kernels on this
// machine sustain 3.2-6.3 TB/s (round 2, m13). v12 keeps round-12's v9
// geometry (full-x y-slab layers, 3-slot rolling window, NB=8192 bins
// keyed (zl, yl>>3)) but stages via global_load_dwordx4 -> VGPR ->
// ds_write: per z-step {issue loads(layer zc+3) early -> compute(zc) from
// LDS -> barrier -> ds_write(layer zc+2; compiler inserts the vmcnt wait)
// -> barrier}. Front-end verbatim from round 12 (~26us).

#define NB     8192
#define CAP    512u
#define GBLK   1024
#define LAYERF4 1728              // float4 per layer (9 rows x 192 f4, contiguous)
#define LAYERF  6912              // floats per layer (27648 B)
#define GRIDF4  12582912          // total float4 in grid

// ws layout: binned[8192*512] float4 = 64MB, then cur[8192]
#define CUR_OFF   67108864u
#define NEEDED    (67108864u + 32768u)

typedef float f4v __attribute__((ext_vector_type(4)));
typedef float f2v __attribute__((ext_vector_type(2)));
typedef f4v f4u __attribute__((aligned(8)));
typedef f2v f2u __attribute__((aligned(8)));

__device__ __forceinline__ void cell_of(float p, int& l, float& t) {
    float s = p * 255.0f;
    int v = (int)floorf(s);
    v = v < 0 ? 0 : (v > 254 ? 254 : v);
    l = v;
    t = s - (float)v;
}

// fine bin: K = zl*32 + (yl>>3)  (full x, 8 y-cells, 1 z-cell)
__device__ __forceinline__ int fine_bin3(float px, float py, float pz) {
    int xl, yl, zl; float tx, ty, tz;
    cell_of(px, xl, tx);
    cell_of(py, yl, ty);
    cell_of(pz, zl, tz);
    return (zl << 5) | (yl >> 3);
}

__device__ __forceinline__ void direct_lerp(const float* __restrict__ grid,
                                            float* __restrict__ out, int i,
                                            int xl, int yl, int zl,
                                            float tx, float ty, float tz) {
    int b00 = (zl * 65536 + yl * 256 + xl) * 3;
    int b01 = b00 + 768, b10 = b00 + 196608, b11 = b10 + 768;
    float s00[6], s01[6], s10[6], s11[6];
#pragma unroll
    for (int k = 0; k < 6; ++k) s00[k] = grid[b00 + k];
#pragma unroll
    for (int k = 0; k < 6; ++k) s01[k] = grid[b01 + k];
#pragma unroll
    for (int k = 0; k < 6; ++k) s10[k] = grid[b10 + k];
#pragma unroll
    for (int k = 0; k < 6; ++k) s11[k] = grid[b11 + k];
#pragma unroll
    for (int c = 0; c < 3; ++c) {
        float c00 = s00[c] * (1.0f - tx) + s00[c + 3] * tx;
        float c01 = s01[c] * (1.0f - tx) + s01[c + 3] * tx;
        float c10 = s10[c] * (1.0f - tx) + s10[c + 3] * tx;
        float c11 = s11[c] * (1.0f - tx) + s11[c + 3] * tx;
        float c0 = c00 * (1.0f - ty) + c01 * ty;
        float c1 = c10 * (1.0f - ty) + c11 * ty;
        out[3 * i + c] = c0 * (1.0f - tz) + c1 * tz;
    }
}

// ---------------- pass 0: init cursors to region bases ----------------
__global__ __launch_bounds__(1024) void k_init(unsigned* __restrict__ cur) {
    int i = blockIdx.x * 1024 + threadIdx.x;
    if (i < NB) cur[i] = (unsigned)i * CAP;
}

// ---------------- pass 1: block-aggregated scatter (2 pts/thread) ----------------
__global__ __launch_bounds__(1024) void k_scatter(const float* __restrict__ inp,
                                                  const float* __restrict__ grid,
                                                  float4* __restrict__ binned,
                                                  unsigned* __restrict__ cur,
                                                  float* __restrict__ out, int n) {
    __shared__ unsigned cnt[NB];
    __shared__ unsigned base[NB];
    int t = threadIdx.x;
    int P = n >> 1;
    int stride = gridDim.x * 1024;
    int iters = (P + stride - 1) / stride;

    if ((n & 1) && blockIdx.x == 0 && t == 0) {
        int i = n - 1;
        float px = inp[3 * i], py = inp[3 * i + 1], pz = inp[3 * i + 2];
        int b = fine_bin3(px, py, pz);
        unsigned r = atomicAdd(&cur[b], 1u);
        if (r - (unsigned)b * CAP < CAP) {
            float4 v; v.x = px; v.y = py; v.z = pz; v.w = __uint_as_float((unsigned)i);
            binned[r] = v;
        } else {
            int xl, yl, zl; float tx, ty, tz;
            cell_of(px, xl, tx); cell_of(py, yl, ty); cell_of(pz, zl, tz);
            direct_lerp(grid, out, i, xl, yl, zl, tx, ty, tz);
        }
    }

    for (int it = 0; it < iters; ++it) {
        int pr = it * stride + blockIdx.x * 1024 + t;
        for (int k = t; k < NB; k += 1024) cnt[k] = 0;
        __syncthreads();
        int b0 = 0, b1 = 0; unsigned r0 = 0, r1 = 0;
        float4 p0, p1;
        bool valid = (pr < P);
        if (valid) {
            f4v a = *(const f4u*)(inp + 6 * pr);
            f2v b = *(const f2u*)(inp + 6 * pr + 4);
            p0.x = a.x; p0.y = a.y; p0.z = a.z;
            p0.w = __uint_as_float((unsigned)(2 * pr));
            p1.x = a.w; p1.y = b.x; p1.z = b.y;
            p1.w = __uint_as_float((unsigned)(2 * pr + 1));
            b0 = fine_bin3(p0.x, p0.y, p0.z);
            b1 = fine_bin3(p1.x, p1.y, p1.z);
            r0 = atomicAdd(&cnt[b0], 1u);
            r1 = atomicAdd(&cnt[b1], 1u);
        }
        __syncthreads();
        for (int k = t; k < NB; k += 1024)
            if (cnt[k]) base[k] = atomicAdd(&cur[k], cnt[k]);
        __syncthreads();
        if (valid) {
            unsigned s0 = base[b0] + r0;
            unsigned s1 = base[b1] + r1;
            if (s0 - (unsigned)b0 * CAP < CAP) binned[s0] = p0;
            else {
                int xl, yl, zl; float tx, ty, tz;
                cell_of(p0.x, xl, tx); cell_of(p0.y, yl, ty); cell_of(p0.z, zl, tz);
                direct_lerp(grid, out, 2 * pr, xl, yl, zl, tx, ty, tz);
            }
            if (s1 - (unsigned)b1 * CAP < CAP) binned[s1] = p1;
            else {
                int xl, yl, zl; float tx, ty, tz;
                cell_of(p1.x, xl, tx); cell_of(p1.y, yl, ty); cell_of(p1.z, zl, tz);
                direct_lerp(grid, out, 2 * pr + 1, xl, yl, zl, tx, ty, tz);
            }
        }
        __syncthreads();
    }
}

// ---------------- pass 2: z-walk gather, reg-staged 3-slot window ----------------
// Layer L of this block = grid[z0+L][y0..y0+9)][*] : 1728 contiguous float4.
// Thread t covers f4 index t (R0) and t+1024 (R1, t<704).
#define LOADL(L)                                                        \
    do {                                                                \
        int zg = z0 + (L); if (zg > 255) zg = 255;                      \
        size_t b4 = (size_t)zg * 49152 + (size_t)y0 * 192;              \
        size_t u0 = b4 + (size_t)t;                                     \
        if (u0 > (size_t)(GRIDF4 - 1)) u0 = (size_t)(GRIDF4 - 1);       \
        R0 = *(const f4u*)(grid + u0 * 4);                              \
        if (t < LAYERF4 - 1024) {                                       \
            size_t u1 = b4 + 1024 + (size_t)t;                          \
            if (u1 > (size_t)(GRIDF4 - 1)) u1 = (size_t)(GRIDF4 - 1);   \
            R1 = *(const f4u*)(grid + u1 * 4);                          \
        }                                                               \
    } while (0)

#define WRITEL(slot_)                                                   \
    do {                                                                \
        float* dst = &slab[(slot_) * LAYERF];                           \
        *(f4v*)&dst[(size_t)t * 4] = R0;                                \
        if (t < LAYERF4 - 1024) *(f4v*)&dst[(size_t)(t + 1024) * 4] = R1; \
    } while (0)

__global__ __launch_bounds__(GBLK) void k_gather(const float4* __restrict__ binned,
                                                 const float* __restrict__ grid,
                                                 const unsigned* __restrict__ cur,
                                                 float* __restrict__ out) {
    __shared__ __align__(16) float slab[3 * LAYERF];   // 82944 B
    int t = threadIdx.x;
    // 512 blocks; XCD-chunked: XCD k owns bins [64k, 64k+64) = 2 contiguous
    // z-segments x all y (halo layers shared within the XCD's L2).
    int bin = ((blockIdx.x & 7) << 6) | (blockIdx.x >> 3);   // bijective [0,512)
    int zb = bin >> 5;            // 16 z-segments of 16 cells
    int yb = bin & 31;            // 32 y-bins of 8 cells
    int z0 = zb << 4;
    int y0 = yb << 3;

    f4v R0, R1;

    LOADL(0); WRITEL(0);
    LOADL(1); WRITEL(1);
    LOADL(2);                     // in flight under step 0's compute
    __syncthreads();

    for (int zc = 0; zc < 16; ++zc) {
        int sA = (zc % 3) * LAYERF;
        int sB = ((zc + 1) % 3) * LAYERF;

        int K = ((z0 + zc) << 5) | yb;
        unsigned start = (unsigned)K * CAP;
        unsigned count = cur[K] - start;
        if (count > CAP) count = CAP;

        for (unsigned p = (unsigned)t; p < count; p += (unsigned)GBLK) {
            float4 v = binned[start + p];
            unsigned idx = __float_as_uint(v.w);

            int xl, yl, zl; float tx, ty, tz;
            cell_of(v.x, xl, tx);
            cell_of(v.y, yl, ty);
            cell_of(v.z, zl, tz);
            int row = yl - y0;                 // 0..7

            int o00 = sA + row * 768 + xl * 3;
            int o01 = o00 + 768;
            int o10 = sB + row * 768 + xl * 3;
            int o11 = o10 + 768;

#define SEG_READ(b, s)                                   \
            do {                                         \
                int e_ = (b) & ~1;                       \
                bool d_ = ((b) & 1) != 0;                \
                f2v q0 = *(const f2u*)(&slab[e_]);       \
                f2v q1 = *(const f2u*)(&slab[e_ + 2]);   \
                f2v q2 = *(const f2u*)(&slab[e_ + 4]);   \
                f2v q3 = *(const f2u*)(&slab[e_ + 6]);   \
                s[0] = d_ ? q0.y : q0.x;                 \
                s[1] = d_ ? q1.x : q0.y;                 \
                s[2] = d_ ? q1.y : q1.x;                 \
                s[3] = d_ ? q2.x : q1.y;                 \
                s[4] = d_ ? q2.y : q2.x;                 \
                s[5] = d_ ? q3.x : q2.y;                 \
            } while (0)

            float s00[6], s01[6], s10[6], s11[6];
            SEG_READ(o00, s00);   // (zl,   yl)
            SEG_READ(o01, s01);   // (zl,   yl+1)
            SEG_READ(o10, s10);   // (zl+1, yl)
            SEG_READ(o11, s11);   // (zl+1, yl+1)
#undef SEG_READ

            float o[3];
#pragma unroll
            for (int c = 0; c < 3; ++c) {
                float c00 = s00[c] * (1.0f - tx) + s00[c + 3] * tx;
                float c01 = s01[c] * (1.0f - tx) + s01[c + 3] * tx;
                float c10 = s10[c] * (1.0f - tx) + s10[c + 3] * tx;
                float c11 = s11[c] * (1.0f - tx) + s11[c + 3] * tx;
                float c0 = c00 * (1.0f - ty) + c01 * ty;
                float c1 = c10 * (1.0f - ty) + c11 * ty;
                o[c] = c0 * (1.0f - tz) + c1 * tz;
            }
            float3 w; w.x = o[0]; w.y = o[1]; w.z = o[2];
            *(float3*)(out + 3 * (size_t)idx) = w;
        }

        // Slot (zc+2)%3 was last read at step zc-1; this barrier fences it.
        __syncthreads();
        if (zc <= 14) WRITEL((zc + 2) % 3);   // layer zc+2 (regs loaded last iter;
                                              // compiler inserts the vmcnt wait)
        if (zc <= 13) LOADL(zc + 3);          // fly under next step's compute
        __syncthreads();                      // ds_writes visible (lgkmcnt drain)
    }
}

// ---------------- fallback: direct ----------------
__global__ __launch_bounds__(256) void k_direct(const float* __restrict__ inp,
                                                const float* __restrict__ grid,
                                                float* __restrict__ out, int n) {
    int i = blockIdx.x * blockDim.x + threadIdx.x;
    if (i >= n) return;
    int xl, yl, zl; float tx, ty, tz;
    cell_of(inp[3 * i + 0], xl, tx);
    cell_of(inp[3 * i + 1], yl, ty);
    cell_of(inp[3 * i + 2], zl, tz);
    direct_lerp(grid, out, i, xl, yl, zl, tx, ty, tz);
}

extern "C" void kernel_launch(void* const* d_in, const int* in_sizes, int n_in,
                              void* d_out, int out_size, void* d_ws, size_t ws_size,
                              hipStream_t stream) {
    const float* inp  = (const float*)d_in[0];  // [N][3]
    const float* grid = (const float*)d_in[1];  // [256][256][256][3]
    float* out = (float*)d_out;                 // [N][3]
    int n = in_sizes[0] / 3;

    if (ws_size < (size_t)NEEDED) {
        int blocks = (n + 255) / 256;
        k_direct<<<blocks, 256, 0, stream>>>(inp, grid, out, n);
        return;
    }

    char* ws = (char*)d_ws;
    float4*   binned = (float4*)ws;
    unsigned* cur    = (unsigned*)(ws + CUR_OFF);

    k_init   <<<8,   1024, 0, stream>>>(cur);
    k_scatter<<<512, 1024, 0, stream>>>(inp, grid, binned, cur, out, n);
    k_gather <<<512, GBLK, 0, stream>>>(binned, grid, cur, out);
}